// Round 7
// baseline (939.002 us; speedup 1.0000x reference)
//
#include <hip/hip_runtime.h>

typedef unsigned short u16;
typedef _Float16 f16;
typedef f16 f16x8 __attribute__((ext_vector_type(8)));
typedef float f32x4 __attribute__((ext_vector_type(4)));

#define B_SZ 8
#define LQ 2048
#define LK 2048
#define HD 1024

__device__ __forceinline__ u16 f32_to_f16(float x) {
  f16 h = (f16)x;
  return __builtin_bit_cast(u16, h);
}
__device__ __forceinline__ float f16_to_f32(u16 h) {
  return (float)__builtin_bit_cast(f16, h);
}

__device__ __forceinline__ void gload_lds16(const void* g, void* l) {
  __builtin_amdgcn_global_load_lds(
      (__attribute__((address_space(1))) void*)(g),
      (__attribute__((address_space(3))) void*)(l), 16, 0, 0);
}

// ---------------------------------------------------------------------------
// q [16384][1024] fp32 -> q' [16384][2048] fp16, hi at [m][k], lo at [m][1024+k]
// ---------------------------------------------------------------------------
__global__ __launch_bounds__(256)
void split_concat_k(const float4* __restrict__ x, u16* __restrict__ o, int n4)
{
  int i = blockIdx.x * blockDim.x + threadIdx.x;
  int stride = gridDim.x * blockDim.x;
  for (; i < n4; i += stride) {
    float4 f = x[i];
    int row = i >> 8;            // 256 float4 per 1024-col row
    int c = (i & 255) << 2;
    ushort4 h, l;
    h.x = f32_to_f16(f.x); l.x = f32_to_f16(f.x - f16_to_f32(h.x));
    h.y = f32_to_f16(f.y); l.y = f32_to_f16(f.y - f16_to_f32(h.y));
    h.z = f32_to_f16(f.z); l.z = f32_to_f16(f.z - f16_to_f32(h.z));
    h.w = f32_to_f16(f.w); l.w = f32_to_f16(f.w - f16_to_f32(h.w));
    *(ushort4*)(o + (size_t)row * 2048 + c) = h;
    *(ushort4*)(o + (size_t)row * 2048 + 1024 + c) = l;
  }
}

// fp32 -> fp16 single
__global__ __launch_bounds__(256)
void cvt_f16_k(const float4* __restrict__ x, ushort4* __restrict__ o, int n4)
{
  int i = blockIdx.x * blockDim.x + threadIdx.x;
  int stride = gridDim.x * blockDim.x;
  for (; i < n4; i += stride) {
    float4 f = x[i];
    ushort4 h;
    h.x = f32_to_f16(f.x); h.y = f32_to_f16(f.y);
    h.z = f32_to_f16(f.z); h.w = f32_to_f16(f.w);
    o[i] = h;
  }
}

// ---------------------------------------------------------------------------
// V [B][LK][HD] fp32 -> Vt [B][HD][LK] fp16 (32x32 LDS tile transpose)
// ---------------------------------------------------------------------------
__global__ __launch_bounds__(256)
void vtrans_k(const float* __restrict__ V, u16* __restrict__ Vt)
{
  __shared__ float t[32][33];
  int z = blockIdx.z;
  int tx = threadIdx.x, ty = threadIdx.y;
  int h0 = blockIdx.x * 32, k0 = blockIdx.y * 32;
  const float* Vb = V + (size_t)z * LK * HD;
  u16* Vtb = Vt + (size_t)z * HD * LK;
#pragma unroll
  for (int i = 0; i < 4; ++i)
    t[ty + i * 8][tx] = Vb[(size_t)(k0 + ty + i * 8) * HD + h0 + tx];
  __syncthreads();
#pragma unroll
  for (int i = 0; i < 4; ++i)
    Vtb[(size_t)(h0 + ty + i * 8) * LK + k0 + tx] = f32_to_f16(t[tx][ty + i * 8]);
}

// ---------------------------------------------------------------------------
// 256x256 B^T GEMM, K=2048 (T=64 tiles of BK=32), 4 WAVES (2Mx2N), per-wave
// 128x128 output (acc 8x8 f32x4 = 256 VGPR), 1 wave/SIMD, quad-buffered LDS.
// Schedule per tile t (ONE barrier, ONE counted vmcnt, NO asm lgkmcnt):
//   stage(t+2) [8 gload_lds]; ds_read 16 frags(buf t); 64 MFMA — compiler
//   emits fine-grained lgkmcnt so reads drain UNDER the MFMA cluster;
//   vmcnt(8) [tile t+1 landed, t+2's 8 loads in flight]; s_barrier.
// Races: stage(t+2) writes buf (t+2)&3 = (t-2)&3, whose ds_reads were all
// consumed by tile t-2's MFMAs (compiler waits) before its end barrier.
// vmcnt counts oldest-first (m135): vmcnt(8) == tile t+1 fully landed.
// Tail: t=T-2, T-1 use vmcnt(0). LDS swizzle (0 conflicts, verified R3-R5):
// stored slot = s ^ ((row>>1)&3) on the GLOBAL source, undone on ds_read.
// XCD swizzle: bijective (nwg%8==0).
// ---------------------------------------------------------------------------
template<int MODE>
__global__ __launch_bounds__(256, 1)
void gemm4w(const u16* __restrict__ A, const u16* __restrict__ Bt,
            const float* __restrict__ bias,
            float* __restrict__ Cf, u16* __restrict__ Ch,
            int N, int KB, long batchA, long batchB, long batchC)
{
  constexpr int KA = 2048;
  constexpr int T = 64;
  extern __shared__ u16 smem[];   // 4 bufs x (8192 A + 8192 B) u16 = 128 KB

  // XCD-aware bijective swizzle
  const int gx = gridDim.x, gy = gridDim.y;
  const int nwg = gx * gy * gridDim.z;
  const int flat = ((int)blockIdx.z * gy + blockIdx.y) * gx + blockIdx.x;
  const int qq = nwg >> 3;
  const int w = (flat & 7) * qq + (flat >> 3);
  const int by = w % gy;
  const int tmp = w / gy;
  const int bx = tmp % gx;
  const int z = tmp / gx;

  const u16* pA = A + (size_t)z * batchA;
  const u16* pB = Bt + (size_t)z * batchB;
  const int kmask = KB - 1;

  const int tid = threadIdx.x;
  const int lane = tid & 63;
  const int wave = tid >> 6;      // 0..3
  const int wr = wave >> 1;       // 0..1 (M)
  const int wc = wave & 1;        // 0..1 (N)
  const int m0 = bx * 256;
  const int n0 = by * 256;
  const int lr = lane & 15;
  const int ls = lane >> 4;

  // staging: 8 chunks/thread (4 A + 4 B); chunk c -> row c>>2, 16B slot c&3
  int ca[4];
  size_t aoff[4], boff[4];        // invariant row*K + swizzled slot offsets
#pragma unroll
  for (int j = 0; j < 4; ++j) {
    ca[j] = tid + j * 256;
    int r = ca[j] >> 2;
    int g = ((ca[j] & 3) ^ ((r >> 1) & 3)) << 3;
    aoff[j] = (size_t)(m0 + r) * KA + g;
    boff[j] = (size_t)(n0 + r) * KB + g;
  }

  f32x4 acc[8][8];
  const f32x4 zero4 = {0.f, 0.f, 0.f, 0.f};
#pragma unroll
  for (int i = 0; i < 8; ++i)
#pragma unroll
    for (int j = 0; j < 8; ++j)
      acc[i][j] = zero4;

  // read-side offsets (elements); physical slot lane-constant
  const int slot8 = ((ls ^ ((lr >> 1) & 3)) << 3);
  const int baseA = (wr * 128 + lr) * 32 + slot8;
  const int baseB = 8192 + (wc * 128 + lr) * 32 + slot8;

  auto stage = [&](int t) {
    u16* b = smem + (t & 3) * 16384;
    const int kt = t * 32;
    const int ktb = kt & kmask;
#pragma unroll
    for (int j = 0; j < 4; ++j)
      gload_lds16(pA + aoff[j] + kt, b + ca[j] * 8);
#pragma unroll
    for (int j = 0; j < 4; ++j)
      gload_lds16(pB + boff[j] + ktb, b + 8192 + ca[j] * 8);
  };

  // prologue: tiles 0,1 staged; wait tile 0 (tile 1's 8 loads stay in flight)
  stage(0); stage(1);
  asm volatile("s_waitcnt vmcnt(8)" ::: "memory");
  __builtin_amdgcn_s_barrier();

  for (int t = 0; t < T; ++t) {
    if (t + 2 < T) stage(t + 2);
    const u16* cb = smem + (t & 3) * 16384;
    f16x8 Af[8], Bf[8];
#pragma unroll
    for (int ni = 0; ni < 8; ++ni)
      Bf[ni] = *(const f16x8*)(cb + baseB + ni * 512);
#pragma unroll
    for (int mi = 0; mi < 8; ++mi)
      Af[mi] = *(const f16x8*)(cb + baseA + mi * 512);
    // 64 MFMA; compiler inserts fine-grained lgkmcnt before each consumer
#pragma unroll
    for (int mi = 0; mi < 8; ++mi)
#pragma unroll
      for (int ni = 0; ni < 8; ++ni)
        acc[mi][ni] = __builtin_amdgcn_mfma_f32_16x16x32_f16(Af[mi], Bf[ni], acc[mi][ni], 0, 0, 0);
    if (t < T - 2) asm volatile("s_waitcnt vmcnt(8)" ::: "memory");
    else           asm volatile("s_waitcnt vmcnt(0)" ::: "memory");
    __builtin_amdgcn_s_barrier();
  }

  // epilogue: C/D layout: col = lane&15 (lr), row = ls*4 + r within frag
#pragma unroll
  for (int mi = 0; mi < 8; ++mi) {
#pragma unroll
    for (int ni = 0; ni < 8; ++ni) {
#pragma unroll
      for (int r = 0; r < 4; ++r) {
        int row = m0 + wr * 128 + mi * 16 + ls * 4 + r;
        int col = n0 + wc * 128 + ni * 16 + lr;
        float v = acc[mi][ni][r];
        if (MODE == 0) {
          v += bias[col];
          u16 h = f32_to_f16(v);
          u16 l = f32_to_f16(v - f16_to_f32(h));
          Ch[(size_t)row * (2 * N) + col] = h;
          Ch[(size_t)row * (2 * N) + N + col] = l;
        } else {
          Cf[(size_t)z * batchC + (size_t)row * N + col] = v;
        }
      }
    }
  }
}

// ---------------------------------------------------------------------------
// row softmax over Lk=2048, in place (fp32) + fp16 copy. 1 block (256t) / row.
// ---------------------------------------------------------------------------
__global__ __launch_bounds__(256)
void softmax_k(float* __restrict__ sc, u16* __restrict__ pf)
{
  __shared__ float redm[4], reds[4];
  size_t row = blockIdx.x;
  float* rp = sc + row * (size_t)LK;
  int tid = threadIdx.x;
  int lane = tid & 63, wv = tid >> 6;

  float4 v0 = *(const float4*)(rp + tid * 8);
  float4 v1 = *(const float4*)(rp + tid * 8 + 4);

  float m = fmaxf(fmaxf(fmaxf(v0.x, v0.y), fmaxf(v0.z, v0.w)),
                  fmaxf(fmaxf(v1.x, v1.y), fmaxf(v1.z, v1.w)));
#pragma unroll
  for (int off = 32; off > 0; off >>= 1)
    m = fmaxf(m, __shfl_xor(m, off));
  if (lane == 0) redm[wv] = m;
  __syncthreads();
  m = fmaxf(fmaxf(redm[0], redm[1]), fmaxf(redm[2], redm[3]));

  float e[8];
  e[0] = __expf(v0.x - m); e[1] = __expf(v0.y - m);
  e[2] = __expf(v0.z - m); e[3] = __expf(v0.w - m);
  e[4] = __expf(v1.x - m); e[5] = __expf(v1.y - m);
  e[6] = __expf(v1.z - m); e[7] = __expf(v1.w - m);
  float s = ((e[0] + e[1]) + (e[2] + e[3])) + ((e[4] + e[5]) + (e[6] + e[7]));
#pragma unroll
  for (int off = 32; off > 0; off >>= 1)
    s += __shfl_xor(s, off);
  if (lane == 0) reds[wv] = s;
  __syncthreads();
  s = (reds[0] + reds[1]) + (reds[2] + reds[3]);

  float inv = 1.0f / s;
  float4 p0 = {e[0] * inv, e[1] * inv, e[2] * inv, e[3] * inv};
  float4 p1 = {e[4] * inv, e[5] * inv, e[6] * inv, e[7] * inv};
  *(float4*)(rp + tid * 8) = p0;
  *(float4*)(rp + tid * 8 + 4) = p1;

  u16* pb = pf + row * (size_t)LK + tid * 8;
  ushort4 h0, h1;
  h0.x = f32_to_f16(p0.x); h0.y = f32_to_f16(p0.y);
  h0.z = f32_to_f16(p0.z); h0.w = f32_to_f16(p0.w);
  h1.x = f32_to_f16(p1.x); h1.y = f32_to_f16(p1.y);
  h1.z = f32_to_f16(p1.z); h1.w = f32_to_f16(p1.w);
  *(ushort4*)(pb) = h0;
  *(ushort4*)(pb + 4) = h1;
}

// ---------------------------------------------------------------------------
extern "C" void kernel_launch(void* const* d_in, const int* in_sizes, int n_in,
                              void* d_out, int out_size, void* d_ws, size_t ws_size,
                              hipStream_t stream)
{
  const float* q  = (const float*)d_in[0];
  const float* ky = (const float*)d_in[1];
  const float* vv = (const float*)d_in[2];
  const float* Ww = (const float*)d_in[3];
  const float* Wb = (const float*)d_in[4];
  float* out   = (float*)d_out;                       // [8,2048,1024]
  float* pattn = out + (size_t)B_SZ * LQ * HD;        // [8,2048,2048]

  char* ws = (char*)d_ws;
  u16* qs = (u16*)(ws);                               // q split-concat, 64 MB
  u16* kh = (u16*)(ws + 67108864);                    // key fp16, 32 MB
  u16* wh = (u16*)(ws + 100663296);                   // W fp16, 2 MB
  u16* vt = (u16*)(ws + 102760448);                   // V^T fp16, 32 MB
  u16* qp = (u16*)(ws + 136314880);                   // q_proj split-concat, 64 MB
  u16* pf = (u16*)(ws);                               // p fp16 (reuses qs)

  const int nq4 = (int)((size_t)B_SZ * LQ * HD / 4);  // 4,194,304
  const int nw4 = HD * HD / 4;                        // 262,144

  split_concat_k<<<2048, 256, 0, stream>>>((const float4*)q, qs, nq4);
  cvt_f16_k<<<2048, 256, 0, stream>>>((const float4*)ky, (ushort4*)kh, nq4);
  cvt_f16_k<<<1024, 256, 0, stream>>>((const float4*)Ww, (ushort4*)wh, nw4);
  vtrans_k<<<dim3(HD / 32, LK / 32, B_SZ), dim3(32, 8), 0, stream>>>(vv, vt);

  // GEMM1: q_proj = q @ W^T + b  (A = [qh|ql] K-concat, B masked k&1023)
  gemm4w<0><<<dim3(64, 4, 1), 256, 131072, stream>>>(
      qs, wh, Wb, nullptr, qp,
      HD, HD, 0, 0, 0);

  // GEMM2: scores = q_proj @ key^T -> fp32 into p_attn region
  gemm4w<1><<<dim3(8, 8, 8), 256, 131072, stream>>>(
      qp, kh, nullptr, pattn, nullptr,
      LK, HD, (long)LQ * 2 * HD, (long)LK * HD, (long)LQ * LK);

  // softmax rows, in place + fp16 copy for PV
  softmax_k<<<B_SZ * LQ, 256, 0, stream>>>(pattn, pf);

  // GEMM3: out = p @ V   (Vt is [HD][LK] per batch, KB=2048 -> mask no-op)
  gemm4w<1><<<dim3(8, 4, 8), 256, 131072, stream>>>(
      pf, vt, nullptr, out, nullptr,
      HD, LK, (long)LQ * LK, (long)HD * LK, (long)LQ * HD);
}

// Round 8
// 334.907 us; speedup vs baseline: 2.8038x; 2.8038x over previous
//
#include <hip/hip_runtime.h>

typedef unsigned short u16;
typedef _Float16 f16;
typedef f16 f16x8 __attribute__((ext_vector_type(8)));
typedef float f32x4 __attribute__((ext_vector_type(4)));

#define B_SZ 8
#define LQ 2048
#define LK 2048
#define HD 1024

__device__ __forceinline__ u16 f32_to_f16(float x) {
  f16 h = (f16)x;
  return __builtin_bit_cast(u16, h);
}
__device__ __forceinline__ float f16_to_f32(u16 h) {
  return (float)__builtin_bit_cast(f16, h);
}

__device__ __forceinline__ void gload_lds16(const void* g, void* l) {
  __builtin_amdgcn_global_load_lds(
      (__attribute__((address_space(1))) void*)(g),
      (__attribute__((address_space(3))) void*)(l), 16, 0, 0);
}

// ---------------------------------------------------------------------------
// q [16384][1024] fp32 -> q' [16384][2048] fp16, hi at [m][k], lo at [m][1024+k]
// ---------------------------------------------------------------------------
__global__ __launch_bounds__(256)
void split_concat_k(const float4* __restrict__ x, u16* __restrict__ o, int n4)
{
  int i = blockIdx.x * blockDim.x + threadIdx.x;
  int stride = gridDim.x * blockDim.x;
  for (; i < n4; i += stride) {
    float4 f = x[i];
    int row = i >> 8;            // 256 float4 per 1024-col row
    int c = (i & 255) << 2;
    ushort4 h, l;
    h.x = f32_to_f16(f.x); l.x = f32_to_f16(f.x - f16_to_f32(h.x));
    h.y = f32_to_f16(f.y); l.y = f32_to_f16(f.y - f16_to_f32(h.y));
    h.z = f32_to_f16(f.z); l.z = f32_to_f16(f.z - f16_to_f32(h.z));
    h.w = f32_to_f16(f.w); l.w = f32_to_f16(f.w - f16_to_f32(h.w));
    *(ushort4*)(o + (size_t)row * 2048 + c) = h;
    *(ushort4*)(o + (size_t)row * 2048 + 1024 + c) = l;
  }
}

// fp32 -> fp16 single
__global__ __launch_bounds__(256)
void cvt_f16_k(const float4* __restrict__ x, ushort4* __restrict__ o, int n4)
{
  int i = blockIdx.x * blockDim.x + threadIdx.x;
  int stride = gridDim.x * blockDim.x;
  for (; i < n4; i += stride) {
    float4 f = x[i];
    ushort4 h;
    h.x = f32_to_f16(f.x); h.y = f32_to_f16(f.y);
    h.z = f32_to_f16(f.z); h.w = f32_to_f16(f.w);
    o[i] = h;
  }
}

// ---------------------------------------------------------------------------
// V [B][LK][HD] fp32 -> Vt [B][HD][LK] fp16 (32x32 LDS tile transpose)
// ---------------------------------------------------------------------------
__global__ __launch_bounds__(256)
void vtrans_k(const float* __restrict__ V, u16* __restrict__ Vt)
{
  __shared__ float t[32][33];
  int z = blockIdx.z;
  int tx = threadIdx.x, ty = threadIdx.y;
  int h0 = blockIdx.x * 32, k0 = blockIdx.y * 32;
  const float* Vb = V + (size_t)z * LK * HD;
  u16* Vtb = Vt + (size_t)z * HD * LK;
#pragma unroll
  for (int i = 0; i < 4; ++i)
    t[ty + i * 8][tx] = Vb[(size_t)(k0 + ty + i * 8) * HD + h0 + tx];
  __syncthreads();
#pragma unroll
  for (int i = 0; i < 4; ++i)
    Vtb[(size_t)(h0 + ty + i * 8) * LK + k0 + tx] = f32_to_f16(t[tx][ty + i * 8]);
}

// ---------------------------------------------------------------------------
// 256x256 B^T GEMM, runtime K (T = KA/32 tiles), quad-buffered LDS (128 KB),
// REGISTER-PIPELINED (R4-verified structure, best measured: ~996 TF eff):
//   iter t: stage(t+3)->buf[(t+3)&3]; ds_read(t+1)->Rnxt; MFMA(Rcur);
//           lgkmcnt(0) + vmcnt(4) [t+2 landed, t+3 in flight]; barrier.
// Races: stage(t+3) overwrites buf[(t-1)&3]; its frags were consumed at
// iter t-2's lgkmcnt(0) before that iter's barrier. dsread(t+1) needs tile
// t+1 landed: iter t-1's vmcnt(4). Tail iters use vmcnt(0).
// LDS swizzle (0 conflicts, verified R3-R5): stored slot = s ^ ((row>>1)&3)
// on the GLOBAL source, linear LDS dest, undone on ds_read.
// B k-index masked by KB-1 (GEMM1: A hi|lo K-concat reuses B twice).
// MODE==0: C += bias[n], store fp16 (hi only). MODE==1: store fp32.
// XCD swizzle: bijective (nwg%8==0).
// ---------------------------------------------------------------------------
template<int MODE>
__global__ __launch_bounds__(512, 2)
void gemm256(const u16* __restrict__ A, const u16* __restrict__ Bt,
             const float* __restrict__ bias,
             float* __restrict__ Cf, u16* __restrict__ Ch,
             int N, int KA, int KB, long batchA, long batchB, long batchC)
{
  extern __shared__ u16 smem[];   // 4 bufs x (8192 A + 8192 B) u16 = 128 KB
  const int T = KA >> 5;

  // XCD-aware bijective swizzle
  const int gx = gridDim.x, gy = gridDim.y;
  const int nwg = gx * gy * gridDim.z;
  const int flat = ((int)blockIdx.z * gy + blockIdx.y) * gx + blockIdx.x;
  const int qq = nwg >> 3;
  const int w = (flat & 7) * qq + (flat >> 3);
  const int by = w % gy;
  const int tmp = w / gy;
  const int bx = tmp % gx;
  const int z = tmp / gx;

  const u16* pA = A + (size_t)z * batchA;
  const u16* pB = Bt + (size_t)z * batchB;
  const int kmask = KB - 1;

  const int tid = threadIdx.x;
  const int lane = tid & 63;
  const int wave = tid >> 6;      // 0..7
  const int wr = wave >> 2;       // 0..1  (M)
  const int wc = wave & 3;        // 0..3  (N)
  const int m0 = bx * 256;
  const int n0 = by * 256;
  const int lr = lane & 15;
  const int ls = lane >> 4;

  // staging chunk coords: chunk c = 16B at LDS offset c*16; row=c>>2, slot=c&3
  const int c0 = tid, c1 = tid + 512;
  const int r0 = c0 >> 2, s0 = c0 & 3;
  const int r1 = c1 >> 2, s1 = c1 & 3;
  const int ga0 = ((s0 ^ ((r0 >> 1) & 3)) << 3);
  const int ga1 = ((s1 ^ ((r1 >> 1) & 3)) << 3);

  f32x4 acc[8][4];
  const f32x4 zero4 = {0.f, 0.f, 0.f, 0.f};
#pragma unroll
  for (int i = 0; i < 8; ++i)
#pragma unroll
    for (int j = 0; j < 4; ++j)
      acc[i][j] = zero4;

  // read-side offsets (elements); physical slot lane-constant
  const int slot8 = ((ls ^ ((lr >> 1) & 3)) << 3);
  const int baseA = (wr * 128 + lr) * 32 + slot8;
  const int baseB = 8192 + (wc * 64 + lr) * 32 + slot8;

  auto stage = [&](int t) {
    u16* b = smem + (t & 3) * 16384;
    const int kt = t * 32;
    const int ktb = kt & kmask;
    gload_lds16(pA + (size_t)(m0 + r0) * KA + kt + ga0, b + c0 * 8);
    gload_lds16(pA + (size_t)(m0 + r1) * KA + kt + ga1, b + c1 * 8);
    gload_lds16(pB + (size_t)(n0 + r0) * KB + ktb + ga0, b + 8192 + c0 * 8);
    gload_lds16(pB + (size_t)(n0 + r1) * KB + ktb + ga1, b + 8192 + c1 * 8);
  };

  auto dsread = [&](int t, f16x8* Af, f16x8* Bf) {
    const u16* cb = smem + (t & 3) * 16384;
#pragma unroll
    for (int mi = 0; mi < 8; ++mi)
      Af[mi] = *(const f16x8*)(cb + baseA + mi * 512);
#pragma unroll
    for (int ni = 0; ni < 4; ++ni)
      Bf[ni] = *(const f16x8*)(cb + baseB + ni * 512);
  };

  auto domfma = [&](f16x8* Af, f16x8* Bf) {
    __builtin_amdgcn_s_setprio(1);
#pragma unroll
    for (int ni = 0; ni < 4; ++ni)
#pragma unroll
      for (int mi = 0; mi < 8; ++mi)
        acc[mi][ni] = __builtin_amdgcn_mfma_f32_16x16x32_f16(Af[mi], Bf[ni], acc[mi][ni], 0, 0, 0);
    __builtin_amdgcn_s_setprio(0);
  };

  auto body = [&](int t, f16x8* cA, f16x8* cB, f16x8* nA, f16x8* nB, bool drain) {
    if (t + 3 < T) stage(t + 3);
    dsread(t + 1, nA, nB);
    domfma(cA, cB);
    if (drain) asm volatile("s_waitcnt vmcnt(0) lgkmcnt(0)" ::: "memory");
    else       asm volatile("s_waitcnt vmcnt(4) lgkmcnt(0)" ::: "memory");
    __builtin_amdgcn_sched_barrier(0);
    __builtin_amdgcn_s_barrier();
    __builtin_amdgcn_sched_barrier(0);
  };

  f16x8 RAa[8], RAb[4], RBa[8], RBb[4];

  // prologue: tiles 0,1,2 staged; wait 0,1 landed (tile 2 stays in flight)
  stage(0); stage(1); stage(2);
  asm volatile("s_waitcnt vmcnt(4)" ::: "memory");
  __builtin_amdgcn_s_barrier();
  __builtin_amdgcn_sched_barrier(0);
  dsread(0, RAa, RAb);

  for (int t = 0; t + 4 < T; t += 2) {
    body(t,     RAa, RAb, RBa, RBb, false);
    body(t + 1, RBa, RBb, RAa, RAb, false);
  }
  body(T - 4, RAa, RAb, RBa, RBb, false);
  body(T - 3, RBa, RBb, RAa, RAb, true);   // drain: last tile must land
  body(T - 2, RAa, RAb, RBa, RBb, true);
  domfma(RBa, RBb);                        // tile T-1

  // epilogue: C/D layout: col = lane&15 (lr), row = ls*4 + r within frag
#pragma unroll
  for (int mi = 0; mi < 8; ++mi) {
#pragma unroll
    for (int ni = 0; ni < 4; ++ni) {
#pragma unroll
      for (int r = 0; r < 4; ++r) {
        int row = m0 + wr * 128 + mi * 16 + ls * 4 + r;
        int col = n0 + wc * 64 + ni * 16 + lr;
        float v = acc[mi][ni][r];
        if (MODE == 0) {
          v += bias[col];
          Ch[(size_t)row * N + col] = f32_to_f16(v);
        } else {
          Cf[(size_t)z * batchC + (size_t)row * N + col] = v;
        }
      }
    }
  }
}

// ---------------------------------------------------------------------------
// row softmax over Lk=2048, in place (fp32) + fp16 copy. 1 block (256t) / row.
// ---------------------------------------------------------------------------
__global__ __launch_bounds__(256)
void softmax_k(float* __restrict__ sc, u16* __restrict__ pf)
{
  __shared__ float redm[4], reds[4];
  size_t row = blockIdx.x;
  float* rp = sc + row * (size_t)LK;
  int tid = threadIdx.x;
  int lane = tid & 63, wv = tid >> 6;

  float4 v0 = *(const float4*)(rp + tid * 8);
  float4 v1 = *(const float4*)(rp + tid * 8 + 4);

  float m = fmaxf(fmaxf(fmaxf(v0.x, v0.y), fmaxf(v0.z, v0.w)),
                  fmaxf(fmaxf(v1.x, v1.y), fmaxf(v1.z, v1.w)));
#pragma unroll
  for (int off = 32; off > 0; off >>= 1)
    m = fmaxf(m, __shfl_xor(m, off));
  if (lane == 0) redm[wv] = m;
  __syncthreads();
  m = fmaxf(fmaxf(redm[0], redm[1]), fmaxf(redm[2], redm[3]));

  float e[8];
  e[0] = __expf(v0.x - m); e[1] = __expf(v0.y - m);
  e[2] = __expf(v0.z - m); e[3] = __expf(v0.w - m);
  e[4] = __expf(v1.x - m); e[5] = __expf(v1.y - m);
  e[6] = __expf(v1.z - m); e[7] = __expf(v1.w - m);
  float s = ((e[0] + e[1]) + (e[2] + e[3])) + ((e[4] + e[5]) + (e[6] + e[7]));
#pragma unroll
  for (int off = 32; off > 0; off >>= 1)
    s += __shfl_xor(s, off);
  if (lane == 0) reds[wv] = s;
  __syncthreads();
  s = (reds[0] + reds[1]) + (reds[2] + reds[3]);

  float inv = 1.0f / s;
  float4 p0 = {e[0] * inv, e[1] * inv, e[2] * inv, e[3] * inv};
  float4 p1 = {e[4] * inv, e[5] * inv, e[6] * inv, e[7] * inv};
  *(float4*)(rp + tid * 8) = p0;
  *(float4*)(rp + tid * 8 + 4) = p1;

  u16* pb = pf + row * (size_t)LK + tid * 8;
  ushort4 h0, h1;
  h0.x = f32_to_f16(p0.x); h0.y = f32_to_f16(p0.y);
  h0.z = f32_to_f16(p0.z); h0.w = f32_to_f16(p0.w);
  h1.x = f32_to_f16(p1.x); h1.y = f32_to_f16(p1.y);
  h1.z = f32_to_f16(p1.z); h1.w = f32_to_f16(p1.w);
  *(ushort4*)(pb) = h0;
  *(ushort4*)(pb + 4) = h1;
}

// ---------------------------------------------------------------------------
extern "C" void kernel_launch(void* const* d_in, const int* in_sizes, int n_in,
                              void* d_out, int out_size, void* d_ws, size_t ws_size,
                              hipStream_t stream)
{
  const float* q  = (const float*)d_in[0];
  const float* ky = (const float*)d_in[1];
  const float* vv = (const float*)d_in[2];
  const float* Ww = (const float*)d_in[3];
  const float* Wb = (const float*)d_in[4];
  float* out   = (float*)d_out;                       // [8,2048,1024]
  float* pattn = out + (size_t)B_SZ * LQ * HD;        // [8,2048,2048]

  char* ws = (char*)d_ws;
  u16* qs = (u16*)(ws);                               // q split-concat, 64 MB
  u16* kh = (u16*)(ws + 67108864);                    // key fp16, 32 MB
  u16* wh = (u16*)(ws + 100663296);                   // W fp16, 2 MB
  u16* vt = (u16*)(ws + 102760448);                   // V^T fp16, 32 MB
  u16* qp = (u16*)(ws + 136314880);                   // q_proj fp16 (hi), 32 MB
  u16* pf = (u16*)(ws);                               // p fp16 (reuses qs)

  const int nq4 = (int)((size_t)B_SZ * LQ * HD / 4);  // 4,194,304
  const int nw4 = HD * HD / 4;                        // 262,144

  split_concat_k<<<2048, 256, 0, stream>>>((const float4*)q, qs, nq4);
  cvt_f16_k<<<2048, 256, 0, stream>>>((const float4*)ky, (ushort4*)kh, nq4);
  cvt_f16_k<<<1024, 256, 0, stream>>>((const float4*)Ww, (ushort4*)wh, nw4);
  vtrans_k<<<dim3(HD / 32, LK / 32, B_SZ), dim3(32, 8), 0, stream>>>(vv, vt);

  // GEMM1: q_proj = q @ W^T + b  (A = [qh|ql] K-concat 2048, B masked k&1023)
  //        output fp16 hi only -> qp [16384][1024]
  gemm256<0><<<dim3(64, 4, 1), 512, 131072, stream>>>(
      qs, wh, Wb, nullptr, qp,
      HD, 2048, HD, 0, 0, 0);

  // GEMM2: scores = q_proj @ key^T  (single fp16, K=1024) -> fp32 p_attn
  gemm256<1><<<dim3(8, 8, 8), 512, 131072, stream>>>(
      qp, kh, nullptr, pattn, nullptr,
      LK, 1024, HD, (long)LQ * HD, (long)LK * HD, (long)LQ * LK);

  // softmax rows, in place + fp16 copy for PV
  softmax_k<<<B_SZ * LQ, 256, 0, stream>>>(pattn, pf);

  // GEMM3: out = p @ V   (Vt is [HD][LK] per batch, KB=2048 -> mask no-op)
  gemm256<1><<<dim3(8, 4, 8), 512, 131072, stream>>>(
      pf, vt, nullptr, out, nullptr,
      HD, 2048, LK, (long)LQ * LK, (long)HD * LK, (long)LQ * HD);
}

// Round 9
// 307.865 us; speedup vs baseline: 3.0500x; 1.0878x over previous
//
#include <hip/hip_runtime.h>

typedef unsigned short u16;
typedef _Float16 f16;
typedef f16 f16x8 __attribute__((ext_vector_type(8)));
typedef float f32x4 __attribute__((ext_vector_type(4)));

#define B_SZ 8
#define LQ 2048
#define LK 2048
#define HD 1024

__device__ __forceinline__ u16 f32_to_f16(float x) {
  f16 h = (f16)x;
  return __builtin_bit_cast(u16, h);
}
__device__ __forceinline__ float f16_to_f32(u16 h) {
  return (float)__builtin_bit_cast(f16, h);
}

__device__ __forceinline__ void gload_lds16(const void* g, void* l) {
  __builtin_amdgcn_global_load_lds(
      (__attribute__((address_space(1))) void*)(g),
      (__attribute__((address_space(3))) void*)(l), 16, 0, 0);
}

// fp32 -> fp16 single (float4-vectorized)
__global__ __launch_bounds__(256)
void cvt_f16_k(const float4* __restrict__ x, ushort4* __restrict__ o, int n4)
{
  int i = blockIdx.x * blockDim.x + threadIdx.x;
  int stride = gridDim.x * blockDim.x;
  for (; i < n4; i += stride) {
    float4 f = x[i];
    ushort4 h;
    h.x = f32_to_f16(f.x); h.y = f32_to_f16(f.y);
    h.z = f32_to_f16(f.z); h.w = f32_to_f16(f.w);
    o[i] = h;
  }
}

// ---------------------------------------------------------------------------
// V [B][LK][HD] fp32 -> Vt [B][HD][LK] fp16 (32x32 LDS tile transpose)
// ---------------------------------------------------------------------------
__global__ __launch_bounds__(256)
void vtrans_k(const float* __restrict__ V, u16* __restrict__ Vt)
{
  __shared__ float t[32][33];
  int z = blockIdx.z;
  int tx = threadIdx.x, ty = threadIdx.y;
  int h0 = blockIdx.x * 32, k0 = blockIdx.y * 32;
  const float* Vb = V + (size_t)z * LK * HD;
  u16* Vtb = Vt + (size_t)z * HD * LK;
#pragma unroll
  for (int i = 0; i < 4; ++i)
    t[ty + i * 8][tx] = Vb[(size_t)(k0 + ty + i * 8) * HD + h0 + tx];
  __syncthreads();
#pragma unroll
  for (int i = 0; i < 4; ++i)
    Vtb[(size_t)(h0 + ty + i * 8) * LK + k0 + tx] = f32_to_f16(t[tx][ty + i * 8]);
}

// ---------------------------------------------------------------------------
// 256x256 B^T GEMM, runtime K (T = KA/32 tiles), quad-buffered LDS (128 KB),
// REGISTER-PIPELINED (R4-verified structure, ~1 TF effective):
//   iter t: stage(t+3)->buf[(t+3)&3]; ds_read(t+1)->Rnxt; MFMA(Rcur);
//           lgkmcnt(0) + vmcnt(4) [t+2 landed, t+3 in flight]; barrier.
// Races: stage(t+3) overwrites buf[(t-1)&3]; its frags were consumed at
// iter t-2's lgkmcnt(0) before that iter's barrier. dsread(t+1) needs tile
// t+1 landed: iter t-1's vmcnt(4). Tail iters use vmcnt(0).
// LDS swizzle (0 conflicts, verified R3-R7): stored slot = s ^ ((row>>1)&3)
// on the GLOBAL source, linear LDS dest, undone on ds_read.
// B k-index masked by KB-1 (mask no-op when KA==KB).
// MODE==0: C += bias[n], store fp16. MODE==1: store fp32.
// XCD swizzle: bijective (nwg%8==0).
// ---------------------------------------------------------------------------
template<int MODE>
__global__ __launch_bounds__(512, 2)
void gemm256(const u16* __restrict__ A, const u16* __restrict__ Bt,
             const float* __restrict__ bias,
             float* __restrict__ Cf, u16* __restrict__ Ch,
             int N, int KA, int KB, long batchA, long batchB, long batchC)
{
  extern __shared__ u16 smem[];   // 4 bufs x (8192 A + 8192 B) u16 = 128 KB
  const int T = KA >> 5;

  // XCD-aware bijective swizzle
  const int gx = gridDim.x, gy = gridDim.y;
  const int nwg = gx * gy * gridDim.z;
  const int flat = ((int)blockIdx.z * gy + blockIdx.y) * gx + blockIdx.x;
  const int qq = nwg >> 3;
  const int w = (flat & 7) * qq + (flat >> 3);
  const int by = w % gy;
  const int tmp = w / gy;
  const int bx = tmp % gx;
  const int z = tmp / gx;

  const u16* pA = A + (size_t)z * batchA;
  const u16* pB = Bt + (size_t)z * batchB;
  const int kmask = KB - 1;

  const int tid = threadIdx.x;
  const int lane = tid & 63;
  const int wave = tid >> 6;      // 0..7
  const int wr = wave >> 2;       // 0..1  (M)
  const int wc = wave & 3;        // 0..3  (N)
  const int m0 = bx * 256;
  const int n0 = by * 256;
  const int lr = lane & 15;
  const int ls = lane >> 4;

  // staging chunk coords: chunk c = 16B at LDS offset c*16; row=c>>2, slot=c&3
  const int c0 = tid, c1 = tid + 512;
  const int r0 = c0 >> 2, s0 = c0 & 3;
  const int r1 = c1 >> 2, s1 = c1 & 3;
  const int ga0 = ((s0 ^ ((r0 >> 1) & 3)) << 3);
  const int ga1 = ((s1 ^ ((r1 >> 1) & 3)) << 3);

  f32x4 acc[8][4];
  const f32x4 zero4 = {0.f, 0.f, 0.f, 0.f};
#pragma unroll
  for (int i = 0; i < 8; ++i)
#pragma unroll
    for (int j = 0; j < 4; ++j)
      acc[i][j] = zero4;

  // read-side offsets (elements); physical slot lane-constant
  const int slot8 = ((ls ^ ((lr >> 1) & 3)) << 3);
  const int baseA = (wr * 128 + lr) * 32 + slot8;
  const int baseB = 8192 + (wc * 64 + lr) * 32 + slot8;

  auto stage = [&](int t) {
    u16* b = smem + (t & 3) * 16384;
    const int kt = t * 32;
    const int ktb = kt & kmask;
    gload_lds16(pA + (size_t)(m0 + r0) * KA + kt + ga0, b + c0 * 8);
    gload_lds16(pA + (size_t)(m0 + r1) * KA + kt + ga1, b + c1 * 8);
    gload_lds16(pB + (size_t)(n0 + r0) * KB + ktb + ga0, b + 8192 + c0 * 8);
    gload_lds16(pB + (size_t)(n0 + r1) * KB + ktb + ga1, b + 8192 + c1 * 8);
  };

  auto dsread = [&](int t, f16x8* Af, f16x8* Bf) {
    const u16* cb = smem + (t & 3) * 16384;
#pragma unroll
    for (int mi = 0; mi < 8; ++mi)
      Af[mi] = *(const f16x8*)(cb + baseA + mi * 512);
#pragma unroll
    for (int ni = 0; ni < 4; ++ni)
      Bf[ni] = *(const f16x8*)(cb + baseB + ni * 512);
  };

  auto domfma = [&](f16x8* Af, f16x8* Bf) {
    __builtin_amdgcn_s_setprio(1);
#pragma unroll
    for (int ni = 0; ni < 4; ++ni)
#pragma unroll
      for (int mi = 0; mi < 8; ++mi)
        acc[mi][ni] = __builtin_amdgcn_mfma_f32_16x16x32_f16(Af[mi], Bf[ni], acc[mi][ni], 0, 0, 0);
    __builtin_amdgcn_s_setprio(0);
  };

  auto body = [&](int t, f16x8* cA, f16x8* cB, f16x8* nA, f16x8* nB, bool drain) {
    if (t + 3 < T) stage(t + 3);
    dsread(t + 1, nA, nB);
    domfma(cA, cB);
    if (drain) asm volatile("s_waitcnt vmcnt(0) lgkmcnt(0)" ::: "memory");
    else       asm volatile("s_waitcnt vmcnt(4) lgkmcnt(0)" ::: "memory");
    __builtin_amdgcn_sched_barrier(0);
    __builtin_amdgcn_s_barrier();
    __builtin_amdgcn_sched_barrier(0);
  };

  f16x8 RAa[8], RAb[4], RBa[8], RBb[4];

  // prologue: tiles 0,1,2 staged; wait 0,1 landed (tile 2 stays in flight)
  stage(0); stage(1); stage(2);
  asm volatile("s_waitcnt vmcnt(4)" ::: "memory");
  __builtin_amdgcn_s_barrier();
  __builtin_amdgcn_sched_barrier(0);
  dsread(0, RAa, RAb);

  for (int t = 0; t + 4 < T; t += 2) {
    body(t,     RAa, RAb, RBa, RBb, false);
    body(t + 1, RBa, RBb, RAa, RAb, false);
  }
  body(T - 4, RAa, RAb, RBa, RBb, false);
  body(T - 3, RBa, RBb, RAa, RAb, true);   // drain: last tile must land
  body(T - 2, RAa, RAb, RBa, RBb, true);
  domfma(RBa, RBb);                        // tile T-1

  // epilogue: C/D layout: col = lane&15 (lr), row = ls*4 + r within frag
#pragma unroll
  for (int mi = 0; mi < 8; ++mi) {
#pragma unroll
    for (int ni = 0; ni < 4; ++ni) {
#pragma unroll
      for (int r = 0; r < 4; ++r) {
        int row = m0 + wr * 128 + mi * 16 + ls * 4 + r;
        int col = n0 + wc * 64 + ni * 16 + lr;
        float v = acc[mi][ni][r];
        if (MODE == 0) {
          v += bias[col];
          Ch[(size_t)row * N + col] = f32_to_f16(v);
        } else {
          Cf[(size_t)z * batchC + (size_t)row * N + col] = v;
        }
      }
    }
  }
}

// ---------------------------------------------------------------------------
// row softmax over Lk=2048, in place (fp32) + fp16 copy. 1 block (256t) / row.
// ---------------------------------------------------------------------------
__global__ __launch_bounds__(256)
void softmax_k(float* __restrict__ sc, u16* __restrict__ pf)
{
  __shared__ float redm[4], reds[4];
  size_t row = blockIdx.x;
  float* rp = sc + row * (size_t)LK;
  int tid = threadIdx.x;
  int lane = tid & 63, wv = tid >> 6;

  float4 v0 = *(const float4*)(rp + tid * 8);
  float4 v1 = *(const float4*)(rp + tid * 8 + 4);

  float m = fmaxf(fmaxf(fmaxf(v0.x, v0.y), fmaxf(v0.z, v0.w)),
                  fmaxf(fmaxf(v1.x, v1.y), fmaxf(v1.z, v1.w)));
#pragma unroll
  for (int off = 32; off > 0; off >>= 1)
    m = fmaxf(m, __shfl_xor(m, off));
  if (lane == 0) redm[wv] = m;
  __syncthreads();
  m = fmaxf(fmaxf(redm[0], redm[1]), fmaxf(redm[2], redm[3]));

  float e[8];
  e[0] = __expf(v0.x - m); e[1] = __expf(v0.y - m);
  e[2] = __expf(v0.z - m); e[3] = __expf(v0.w - m);
  e[4] = __expf(v1.x - m); e[5] = __expf(v1.y - m);
  e[6] = __expf(v1.z - m); e[7] = __expf(v1.w - m);
  float s = ((e[0] + e[1]) + (e[2] + e[3])) + ((e[4] + e[5]) + (e[6] + e[7]));
#pragma unroll
  for (int off = 32; off > 0; off >>= 1)
    s += __shfl_xor(s, off);
  if (lane == 0) reds[wv] = s;
  __syncthreads();
  s = (reds[0] + reds[1]) + (reds[2] + reds[3]);

  float inv = 1.0f / s;
  float4 p0 = {e[0] * inv, e[1] * inv, e[2] * inv, e[3] * inv};
  float4 p1 = {e[4] * inv, e[5] * inv, e[6] * inv, e[7] * inv};
  *(float4*)(rp + tid * 8) = p0;
  *(float4*)(rp + tid * 8 + 4) = p1;

  u16* pb = pf + row * (size_t)LK + tid * 8;
  ushort4 h0, h1;
  h0.x = f32_to_f16(p0.x); h0.y = f32_to_f16(p0.y);
  h0.z = f32_to_f16(p0.z); h0.w = f32_to_f16(p0.w);
  h1.x = f32_to_f16(p1.x); h1.y = f32_to_f16(p1.y);
  h1.z = f32_to_f16(p1.z); h1.w = f32_to_f16(p1.w);
  *(ushort4*)(pb) = h0;
  *(ushort4*)(pb + 4) = h1;
}

// ---------------------------------------------------------------------------
extern "C" void kernel_launch(void* const* d_in, const int* in_sizes, int n_in,
                              void* d_out, int out_size, void* d_ws, size_t ws_size,
                              hipStream_t stream)
{
  const float* q  = (const float*)d_in[0];
  const float* ky = (const float*)d_in[1];
  const float* vv = (const float*)d_in[2];
  const float* Ww = (const float*)d_in[3];
  const float* Wb = (const float*)d_in[4];
  float* out   = (float*)d_out;                       // [8,2048,1024]
  float* pattn = out + (size_t)B_SZ * LQ * HD;        // [8,2048,2048]

  char* ws = (char*)d_ws;
  u16* qh = (u16*)(ws);                               // q fp16, 32 MB
  u16* kh = (u16*)(ws + 33554432);                    // key fp16, 32 MB
  u16* wh = (u16*)(ws + 67108864);                    // W fp16, 2 MB
  u16* vt = (u16*)(ws + 69206016);                    // V^T fp16, 32 MB
  u16* qp = (u16*)(ws + 102760448);                   // q_proj fp16, 32 MB
  u16* pf = (u16*)(ws);                               // p fp16, 67 MB (reuses
                                                      // qh+kh+wh, dead by then)

  const int nq4 = (int)((size_t)B_SZ * LQ * HD / 4);  // 4,194,304
  const int nw4 = HD * HD / 4;                        // 262,144

  cvt_f16_k<<<2048, 256, 0, stream>>>((const float4*)q, (ushort4*)qh, nq4);
  cvt_f16_k<<<2048, 256, 0, stream>>>((const float4*)ky, (ushort4*)kh, nq4);
  cvt_f16_k<<<1024, 256, 0, stream>>>((const float4*)Ww, (ushort4*)wh, nw4);
  vtrans_k<<<dim3(HD / 32, LK / 32, B_SZ), dim3(32, 8), 0, stream>>>(vv, vt);

  // GEMM1: q_proj = q @ W^T + b  (single fp16, K=1024) -> fp16 qp
  gemm256<0><<<dim3(64, 4, 1), 512, 131072, stream>>>(
      qh, wh, Wb, nullptr, qp,
      HD, 1024, HD, 0, 0, 0);

  // GEMM2: scores = q_proj @ key^T  (single fp16, K=1024) -> fp32 p_attn
  gemm256<1><<<dim3(8, 8, 8), 512, 131072, stream>>>(
      qp, kh, nullptr, pattn, nullptr,
      LK, 1024, HD, (long)LQ * HD, (long)LK * HD, (long)LQ * LK);

  // softmax rows, in place + fp16 copy for PV
  softmax_k<<<B_SZ * LQ, 256, 0, stream>>>(pattn, pf);

  // GEMM3: out = p @ V   (Vt is [HD][LK] per batch, KB=2048 -> mask no-op)
  gemm256<1><<<dim3(8, 4, 8), 512, 131072, stream>>>(
      pf, vt, nullptr, out, nullptr,
      HD, 2048, LK, (long)LQ * LK, (long)HD * LK, (long)LQ * HD);
}

// Round 10
// 300.658 us; speedup vs baseline: 3.1232x; 1.0240x over previous
//
#include <hip/hip_runtime.h>

typedef unsigned short u16;
typedef _Float16 f16;
typedef f16 f16x8 __attribute__((ext_vector_type(8)));
typedef float f32x4 __attribute__((ext_vector_type(4)));

#define B_SZ 8
#define LQ 2048
#define LK 2048
#define HD 1024

__device__ __forceinline__ u16 f32_to_f16(float x) {
  f16 h = (f16)x;
  return __builtin_bit_cast(u16, h);
}
__device__ __forceinline__ float f16_to_f32(u16 h) {
  return (float)__builtin_bit_cast(f16, h);
}

__device__ __forceinline__ void gload_lds16(const void* g, void* l) {
  __builtin_amdgcn_global_load_lds(
      (__attribute__((address_space(1))) void*)(g),
      (__attribute__((address_space(3))) void*)(l), 16, 0, 0);
}

// ---------------------------------------------------------------------------
// fused fp32 -> fp16 convert for q, key, W (three regions, one launch)
// ---------------------------------------------------------------------------
__global__ __launch_bounds__(256)
void cvt3_k(const float4* __restrict__ a, ushort4* __restrict__ oa, int na4,
            const float4* __restrict__ b, ushort4* __restrict__ ob, int nb4,
            const float4* __restrict__ c, ushort4* __restrict__ oc, int nc4)
{
  int total = na4 + nb4 + nc4;
  int i = blockIdx.x * blockDim.x + threadIdx.x;
  int stride = gridDim.x * blockDim.x;
  for (; i < total; i += stride) {
    const float4* src; ushort4* dst; int j;
    if (i < na4)            { src = a; dst = oa; j = i; }
    else if (i < na4 + nb4) { src = b; dst = ob; j = i - na4; }
    else                    { src = c; dst = oc; j = i - na4 - nb4; }
    float4 f = src[j];
    ushort4 h;
    h.x = f32_to_f16(f.x); h.y = f32_to_f16(f.y);
    h.z = f32_to_f16(f.z); h.w = f32_to_f16(f.w);
    dst[j] = h;
  }
}

// ---------------------------------------------------------------------------
// V [B][LK][HD] fp32 -> Vt [B][HD][LK] fp16 (32x32 LDS tile transpose)
// ---------------------------------------------------------------------------
__global__ __launch_bounds__(256)
void vtrans_k(const float* __restrict__ V, u16* __restrict__ Vt)
{
  __shared__ float t[32][33];
  int z = blockIdx.z;
  int tx = threadIdx.x, ty = threadIdx.y;
  int h0 = blockIdx.x * 32, k0 = blockIdx.y * 32;
  const float* Vb = V + (size_t)z * LK * HD;
  u16* Vtb = Vt + (size_t)z * HD * LK;
#pragma unroll
  for (int i = 0; i < 4; ++i)
    t[ty + i * 8][tx] = Vb[(size_t)(k0 + ty + i * 8) * HD + h0 + tx];
  __syncthreads();
#pragma unroll
  for (int i = 0; i < 4; ++i)
    Vtb[(size_t)(h0 + ty + i * 8) * LK + k0 + tx] = f32_to_f16(t[tx][ty + i * 8]);
}

// ---------------------------------------------------------------------------
// 256x256 B^T GEMM, runtime K (T = KA/32 tiles), quad-buffered LDS (128 KB),
// REGISTER-PIPELINED (R4 structure) + ISSUE-ORDER PIN (this round):
//   iter t: stage(t+3)->buf[(t+3)&3]; ds_read(t+1)->Rnxt; sched_barrier(0)
//           [pins ds_reads BEFORE the MFMA cluster so the LDS pipe drains
//            under the MFMAs instead of after them]; MFMA(Rcur);
//           lgkmcnt(0) + vmcnt(4) [t+2 landed, t+3 in flight]; barrier.
// Races: stage(t+3) overwrites buf[(t-1)&3]; its frags were consumed at
// iter t-2's lgkmcnt(0) before that iter's barrier. dsread(t+1) needs tile
// t+1 landed: iter t-1's vmcnt(4). Tail iters use vmcnt(0).
// LDS swizzle (0 conflicts, verified R3-R8): stored slot = s ^ ((row>>1)&3)
// on the GLOBAL source, linear LDS dest, undone on ds_read.
// B k-index masked by KB-1 (mask no-op when KA==KB).
// MODE==0: C += bias[n], store fp16. MODE==1: store fp32.
// XCD swizzle: bijective (nwg%8==0).
// ---------------------------------------------------------------------------
template<int MODE>
__global__ __launch_bounds__(512, 2)
void gemm256(const u16* __restrict__ A, const u16* __restrict__ Bt,
             const float* __restrict__ bias,
             float* __restrict__ Cf, u16* __restrict__ Ch,
             int N, int KA, int KB, long batchA, long batchB, long batchC)
{
  extern __shared__ u16 smem[];   // 4 bufs x (8192 A + 8192 B) u16 = 128 KB
  const int T = KA >> 5;

  // XCD-aware bijective swizzle
  const int gx = gridDim.x, gy = gridDim.y;
  const int nwg = gx * gy * gridDim.z;
  const int flat = ((int)blockIdx.z * gy + blockIdx.y) * gx + blockIdx.x;
  const int qq = nwg >> 3;
  const int w = (flat & 7) * qq + (flat >> 3);
  const int by = w % gy;
  const int tmp = w / gy;
  const int bx = tmp % gx;
  const int z = tmp / gx;

  const u16* pA = A + (size_t)z * batchA;
  const u16* pB = Bt + (size_t)z * batchB;
  const int kmask = KB - 1;

  const int tid = threadIdx.x;
  const int lane = tid & 63;
  const int wave = tid >> 6;      // 0..7
  const int wr = wave >> 2;       // 0..1  (M)
  const int wc = wave & 3;        // 0..3  (N)
  const int m0 = bx * 256;
  const int n0 = by * 256;
  const int lr = lane & 15;
  const int ls = lane >> 4;

  // staging chunk coords: chunk c = 16B at LDS offset c*16; row=c>>2, slot=c&3
  const int c0 = tid, c1 = tid + 512;
  const int r0 = c0 >> 2, s0 = c0 & 3;
  const int r1 = c1 >> 2, s1 = c1 & 3;
  const int ga0 = ((s0 ^ ((r0 >> 1) & 3)) << 3);
  const int ga1 = ((s1 ^ ((r1 >> 1) & 3)) << 3);

  f32x4 acc[8][4];
  const f32x4 zero4 = {0.f, 0.f, 0.f, 0.f};
#pragma unroll
  for (int i = 0; i < 8; ++i)
#pragma unroll
    for (int j = 0; j < 4; ++j)
      acc[i][j] = zero4;

  // read-side offsets (elements); physical slot lane-constant
  const int slot8 = ((ls ^ ((lr >> 1) & 3)) << 3);
  const int baseA = (wr * 128 + lr) * 32 + slot8;
  const int baseB = 8192 + (wc * 64 + lr) * 32 + slot8;

  auto stage = [&](int t) {
    u16* b = smem + (t & 3) * 16384;
    const int kt = t * 32;
    const int ktb = kt & kmask;
    gload_lds16(pA + (size_t)(m0 + r0) * KA + kt + ga0, b + c0 * 8);
    gload_lds16(pA + (size_t)(m0 + r1) * KA + kt + ga1, b + c1 * 8);
    gload_lds16(pB + (size_t)(n0 + r0) * KB + ktb + ga0, b + 8192 + c0 * 8);
    gload_lds16(pB + (size_t)(n0 + r1) * KB + ktb + ga1, b + 8192 + c1 * 8);
  };

  auto dsread = [&](int t, f16x8* Af, f16x8* Bf) {
    const u16* cb = smem + (t & 3) * 16384;
#pragma unroll
    for (int mi = 0; mi < 8; ++mi)
      Af[mi] = *(const f16x8*)(cb + baseA + mi * 512);
#pragma unroll
    for (int ni = 0; ni < 4; ++ni)
      Bf[ni] = *(const f16x8*)(cb + baseB + ni * 512);
  };

  auto domfma = [&](f16x8* Af, f16x8* Bf) {
    __builtin_amdgcn_s_setprio(1);
#pragma unroll
    for (int ni = 0; ni < 4; ++ni)
#pragma unroll
      for (int mi = 0; mi < 8; ++mi)
        acc[mi][ni] = __builtin_amdgcn_mfma_f32_16x16x32_f16(Af[mi], Bf[ni], acc[mi][ni], 0, 0, 0);
    __builtin_amdgcn_s_setprio(0);
  };

  auto body = [&](int t, f16x8* cA, f16x8* cB, f16x8* nA, f16x8* nB, bool drain) {
    if (t + 3 < T) stage(t + 3);
    dsread(t + 1, nA, nB);
    // PIN: ds_reads must be issued before the MFMA cluster (prevents the
    // scheduler sinking them after it to shorten live ranges — that
    // serializes LDS after MFMA and was the measured 44% ceiling).
    __builtin_amdgcn_sched_barrier(0);
    domfma(cA, cB);
    if (drain) asm volatile("s_waitcnt vmcnt(0) lgkmcnt(0)" ::: "memory");
    else       asm volatile("s_waitcnt vmcnt(4) lgkmcnt(0)" ::: "memory");
    __builtin_amdgcn_sched_barrier(0);
    __builtin_amdgcn_s_barrier();
    __builtin_amdgcn_sched_barrier(0);
  };

  f16x8 RAa[8], RAb[4], RBa[8], RBb[4];

  // prologue: tiles 0,1,2 staged; wait 0,1 landed (tile 2 stays in flight)
  stage(0); stage(1); stage(2);
  asm volatile("s_waitcnt vmcnt(4)" ::: "memory");
  __builtin_amdgcn_s_barrier();
  __builtin_amdgcn_sched_barrier(0);
  dsread(0, RAa, RAb);

  for (int t = 0; t + 4 < T; t += 2) {
    body(t,     RAa, RAb, RBa, RBb, false);
    body(t + 1, RBa, RBb, RAa, RAb, false);
  }
  body(T - 4, RAa, RAb, RBa, RBb, false);
  body(T - 3, RBa, RBb, RAa, RAb, true);   // drain: last tile must land
  body(T - 2, RAa, RAb, RBa, RBb, true);
  domfma(RBa, RBb);                        // tile T-1

  // epilogue: C/D layout: col = lane&15 (lr), row = ls*4 + r within frag
#pragma unroll
  for (int mi = 0; mi < 8; ++mi) {
#pragma unroll
    for (int ni = 0; ni < 4; ++ni) {
#pragma unroll
      for (int r = 0; r < 4; ++r) {
        int row = m0 + wr * 128 + mi * 16 + ls * 4 + r;
        int col = n0 + wc * 64 + ni * 16 + lr;
        float v = acc[mi][ni][r];
        if (MODE == 0) {
          v += bias[col];
          Ch[(size_t)row * N + col] = f32_to_f16(v);
        } else {
          Cf[(size_t)z * batchC + (size_t)row * N + col] = v;
        }
      }
    }
  }
}

// ---------------------------------------------------------------------------
// row softmax over Lk=2048, in place (fp32) + fp16 copy. 1 block (256t) / row.
// ---------------------------------------------------------------------------
__global__ __launch_bounds__(256)
void softmax_k(float* __restrict__ sc, u16* __restrict__ pf)
{
  __shared__ float redm[4], reds[4];
  size_t row = blockIdx.x;
  float* rp = sc + row * (size_t)LK;
  int tid = threadIdx.x;
  int lane = tid & 63, wv = tid >> 6;

  float4 v0 = *(const float4*)(rp + tid * 8);
  float4 v1 = *(const float4*)(rp + tid * 8 + 4);

  float m = fmaxf(fmaxf(fmaxf(v0.x, v0.y), fmaxf(v0.z, v0.w)),
                  fmaxf(fmaxf(v1.x, v1.y), fmaxf(v1.z, v1.w)));
#pragma unroll
  for (int off = 32; off > 0; off >>= 1)
    m = fmaxf(m, __shfl_xor(m, off));
  if (lane == 0) redm[wv] = m;
  __syncthreads();
  m = fmaxf(fmaxf(redm[0], redm[1]), fmaxf(redm[2], redm[3]));

  float e[8];
  e[0] = __expf(v0.x - m); e[1] = __expf(v0.y - m);
  e[2] = __expf(v0.z - m); e[3] = __expf(v0.w - m);
  e[4] = __expf(v1.x - m); e[5] = __expf(v1.y - m);
  e[6] = __expf(v1.z - m); e[7] = __expf(v1.w - m);
  float s = ((e[0] + e[1]) + (e[2] + e[3])) + ((e[4] + e[5]) + (e[6] + e[7]));
#pragma unroll
  for (int off = 32; off > 0; off >>= 1)
    s += __shfl_xor(s, off);
  if (lane == 0) reds[wv] = s;
  __syncthreads();
  s = (reds[0] + reds[1]) + (reds[2] + reds[3]);

  float inv = 1.0f / s;
  float4 p0 = {e[0] * inv, e[1] * inv, e[2] * inv, e[3] * inv};
  float4 p1 = {e[4] * inv, e[5] * inv, e[6] * inv, e[7] * inv};
  *(float4*)(rp + tid * 8) = p0;
  *(float4*)(rp + tid * 8 + 4) = p1;

  u16* pb = pf + row * (size_t)LK + tid * 8;
  ushort4 h0, h1;
  h0.x = f32_to_f16(p0.x); h0.y = f32_to_f16(p0.y);
  h0.z = f32_to_f16(p0.z); h0.w = f32_to_f16(p0.w);
  h1.x = f32_to_f16(p1.x); h1.y = f32_to_f16(p1.y);
  h1.z = f32_to_f16(p1.z); h1.w = f32_to_f16(p1.w);
  *(ushort4*)(pb) = h0;
  *(ushort4*)(pb + 4) = h1;
}

// ---------------------------------------------------------------------------
extern "C" void kernel_launch(void* const* d_in, const int* in_sizes, int n_in,
                              void* d_out, int out_size, void* d_ws, size_t ws_size,
                              hipStream_t stream)
{
  const float* q  = (const float*)d_in[0];
  const float* ky = (const float*)d_in[1];
  const float* vv = (const float*)d_in[2];
  const float* Ww = (const float*)d_in[3];
  const float* Wb = (const float*)d_in[4];
  float* out   = (float*)d_out;                       // [8,2048,1024]
  float* pattn = out + (size_t)B_SZ * LQ * HD;        // [8,2048,2048]

  char* ws = (char*)d_ws;
  u16* qh = (u16*)(ws);                               // q fp16, 32 MB
  u16* kh = (u16*)(ws + 33554432);                    // key fp16, 32 MB
  u16* wh = (u16*)(ws + 67108864);                    // W fp16, 2 MB
  u16* vt = (u16*)(ws + 69206016);                    // V^T fp16, 32 MB
  u16* qp = (u16*)(ws + 102760448);                   // q_proj fp16, 32 MB
  u16* pf = (u16*)(ws);                               // p fp16, 67 MB (reuses
                                                      // qh+kh+wh, dead by then)

  const int nq4 = (int)((size_t)B_SZ * LQ * HD / 4);  // 4,194,304
  const int nw4 = HD * HD / 4;                        // 262,144

  cvt3_k<<<4096, 256, 0, stream>>>(
      (const float4*)q, (ushort4*)qh, nq4,
      (const float4*)ky, (ushort4*)kh, nq4,
      (const float4*)Ww, (ushort4*)wh, nw4);
  vtrans_k<<<dim3(HD / 32, LK / 32, B_SZ), dim3(32, 8), 0, stream>>>(vv, vt);

  // GEMM1: q_proj = q @ W^T + b  (single fp16, K=1024) -> fp16 qp
  gemm256<0><<<dim3(64, 4, 1), 512, 131072, stream>>>(
      qh, wh, Wb, nullptr, qp,
      HD, 1024, HD, 0, 0, 0);

  // GEMM2: scores = q_proj @ key^T  (single fp16, K=1024) -> fp32 p_attn
  gemm256<1><<<dim3(8, 8, 8), 512, 131072, stream>>>(
      qp, kh, nullptr, pattn, nullptr,
      LK, 1024, HD, (long)LQ * HD, (long)LK * HD, (long)LQ * LK);

  // softmax rows, in place + fp16 copy for PV
  softmax_k<<<B_SZ * LQ, 256, 0, stream>>>(pattn, pf);

  // GEMM3: out = p @ V   (Vt is [HD][LK] per batch, KB=2048 -> mask no-op)
  gemm256<1><<<dim3(8, 4, 8), 512, 131072, stream>>>(
      pf, vt, nullptr, out, nullptr,
      HD, 2048, LK, (long)LQ * LK, (long)HD * LK, (long)LQ * HD);
}